// Round 12
// baseline (322.822 us; speedup 1.0000x reference)
//
#include <hip/hip_runtime.h>
#include <math.h>

#define NN 100000
#define NE 3200000
#define NR 90
#define NB 391          // ceil(NN/256): buckets of 256 nodes (dst>>8)
#define CH 4096         // edges per block in partition passes
#define NCHUNK 782      // ceil(NE/CH)

typedef unsigned int u32;
typedef unsigned short u16;

__device__ inline u32 pack2(float a, float b) {       // bf16(a) lo16, bf16(b) hi16 (RNE)
    u32 ua = __float_as_uint(a); ua += 0x7FFFu + ((ua >> 16) & 1u);
    u32 ub = __float_as_uint(b); ub += 0x7FFFu + ((ub >> 16) & 1u);
    return (ua >> 16) | (ub & 0xFFFF0000u);
}
__device__ inline float unlo(u32 w) { return __uint_as_float(w << 16); }
__device__ inline float unhi(u32 w) { return __uint_as_float(w & 0xFFFF0000u); }

// ---------------- coarse histogram: bucket = dst >> 8 ----------------
__global__ __launch_bounds__(256) void coarse_count_kernel(const int* __restrict__ dst,
                                                           u32* __restrict__ ccnt) {
    __shared__ u32 bh[NB];
    int tid = threadIdx.x;
    for (int b = tid; b < NB; b += 256) bh[b] = 0;
    __syncthreads();
    int c0 = blockIdx.x * CH;
    int c1 = c0 + CH; if (c1 > NE) c1 = NE;
    for (int e = c0 + tid; e < c1; e += 256)
        atomicAdd(&bh[(u32)dst[e] >> 8], 1u);
    __syncthreads();
    for (int b = tid; b < NB; b += 256) {
        u32 c = bh[b];
        if (c) atomicAdd(&ccnt[b], c);
    }
}

// ---------------- exclusive scan of NB coarse counts (1 block) ----------------
__global__ __launch_bounds__(512) void scan_coff_kernel(const u32* __restrict__ ccnt,
                                                        u32* __restrict__ coff,
                                                        u32* __restrict__ ccursor) {
    __shared__ u32 sh[512];
    int tid = threadIdx.x;
    sh[tid] = (tid < NB) ? ccnt[tid] : 0u;
    __syncthreads();
#pragma unroll
    for (int ofs = 1; ofs < 512; ofs <<= 1) {
        u32 v = (tid >= ofs) ? sh[tid - ofs] : 0u;
        __syncthreads();
        sh[tid] += v;
        __syncthreads();
    }
    u32 excl = (tid == 0) ? 0u : sh[tid - 1];
    if (tid < NB) { coff[tid] = excl; ccursor[tid] = excl; }
    if (tid == 0) coff[NB] = NE;
}

// ---------------- pass 1: LDS-staged coarse partition, coalesced run writes ----------------
// tmp entry: (dst&255)<<24 | src<<7 | et
__global__ __launch_bounds__(512) void pass1_kernel(const int* __restrict__ src,
                                                    const int* __restrict__ dst,
                                                    const int* __restrict__ et,
                                                    u32* __restrict__ ccursor,
                                                    u32* __restrict__ tmp) {
    __shared__ u32 cntA[NB];
    __shared__ u32 lcur[NB];
    __shared__ u32 delta[NB];
    __shared__ u32 scanS[512];
    __shared__ u32 lrecs[CH];
    __shared__ u16 lbid[CH];
    int tid = threadIdx.x;
    int c0 = blockIdx.x * CH;
    int c1 = c0 + CH; if (c1 > NE) c1 = NE;
    int nloc = c1 - c0;

    if (tid < NB) cntA[tid] = 0;
    __syncthreads();

    for (int e = c0 + tid; e < c1; e += 512)
        atomicAdd(&cntA[(u32)dst[e] >> 8], 1u);
    __syncthreads();

    scanS[tid] = (tid < NB) ? cntA[tid] : 0u;
    __syncthreads();
#pragma unroll
    for (int ofs = 1; ofs < 512; ofs <<= 1) {
        u32 v = (tid >= ofs) ? scanS[tid - ofs] : 0u;
        __syncthreads();
        scanS[tid] += v;
        __syncthreads();
    }
    if (tid < NB) {
        u32 excl = (tid == 0) ? 0u : scanS[tid - 1];
        lcur[tid] = excl;
        u32 c = cntA[tid];
        delta[tid] = c ? (atomicAdd(&ccursor[tid], c) - excl) : 0u;
    }
    __syncthreads();

    for (int e = c0 + tid; e < c1; e += 512) {
        u32 d = (u32)dst[e];
        u32 b = d >> 8;
        u32 pos = atomicAdd(&lcur[b], 1u);
        lrecs[pos] = ((d & 255u) << 24) | ((u32)src[e] << 7) | (u32)et[e];
        lbid[pos] = (u16)b;
    }
    __syncthreads();

    for (int k = tid; k < nloc; k += 512)
        tmp[delta[lbid[k]] + k] = lrecs[k];
}

// ---------------- pass 2: per-bucket fine sort; recs gets cnt<<24 | src<<7 | et ----------------
__global__ __launch_bounds__(512) void pass2_kernel(const u32* __restrict__ tmp,
                                                    const u32* __restrict__ coff,
                                                    u32* __restrict__ off,
                                                    u32* __restrict__ recs,
                                                    const float* __restrict__ x,
                                                    uint2* __restrict__ xb) {
    __shared__ u32 dh[256];
    __shared__ u32 lcur[256];
    __shared__ u32 cnt32[256 * 23];
    __shared__ u32 sh[256];
    int tid = threadIdx.x;
    int b = blockIdx.x;
    u32 r0 = coff[b], r1 = coff[b + 1];

    if (tid < 256) dh[tid] = 0;
    for (int i = tid; i < 256 * 23; i += 512) cnt32[i] = 0;
    __syncthreads();

    for (u32 k = r0 + tid; k < r1; k += 512)
        atomicAdd(&dh[__builtin_nontemporal_load(tmp + k) >> 24], 1u);
    __syncthreads();

    if (tid < 256) sh[tid] = dh[tid];
    __syncthreads();
#pragma unroll
    for (int ofs = 1; ofs < 256; ofs <<= 1) {
        u32 v = (tid >= ofs && tid < 256) ? sh[tid - ofs] : 0u;
        __syncthreads();
        if (tid < 256) sh[tid] += v;
        __syncthreads();
    }
    int n = b * 256 + tid;
    if (tid < 256) {
        u32 excl = (tid == 0) ? 0u : sh[tid - 1];
        if (n < NN) off[n] = r0 + excl;
        lcur[tid] = excl;
    }
    if (b == NB - 1 && tid == 0) off[NN] = NE;
    __syncthreads();

    for (u32 k = r0 + tid; k < r1; k += 512) {
        u32 v = __builtin_nontemporal_load(tmp + k);
        u32 ln = v >> 24;
        u32 rec = v & 0xFFFFFFu;
        u32 rel = v & 127u;
        u32 pos = atomicAdd(&lcur[ln], 1u);
        recs[r0 + pos] = rec;
        atomicAdd(&cnt32[ln * 23 + (rel >> 2)], 1u << ((rel & 3u) * 8u));
    }
    __syncthreads();

    if (tid < 256 && n < NN) {
        u32 start = (tid == 0) ? 0u : sh[tid - 1];
        u32 end = sh[tid];
        for (u32 j = start; j < end; j++) {
            u32 rel = recs[r0 + j] & 127u;
            u32 c = (cnt32[tid * 23 + (rel >> 2)] >> ((rel & 3u) * 8u)) & 255u;
            recs[r0 + j] |= c << 24;
        }
        float4 xv = *(const float4*)(x + (size_t)n * 4);
        xb[n] = make_uint2(pack2(xv.x, xv.y), pack2(xv.z, xv.w));
    }
}

// ======== layer kernels: 8 lanes/node (round-9 structure), NT recs, bf16-only tables ========

// ---------------- layer 1: mean-aggr + root + bias + relu ----------------
__global__ __launch_bounds__(256) void layer1_kernel(
        const u32* __restrict__ off, const u32* __restrict__ recs,
        const uint2* __restrict__ xb,
        const float* __restrict__ x, const float* __restrict__ w1,
        const float* __restrict__ root1, const float* __restrict__ b1,
        uint4* __restrict__ h1b) {
    int gid = blockIdx.x * 256 + threadIdx.x;
    int n = gid >> 3, r = gid & 7;
    if (n >= NN) return;
    float acc[8];
#pragma unroll
    for (int j = 0; j < 8; j++) acc[j] = 0.0f;

    u32 k0 = off[n], k1 = off[n + 1];
    for (u32 k = k0 + r; k < k1; k += 8) {
        u32 rec = __builtin_nontemporal_load(recs + k);
        u32 t = rec & 127u, s = (rec >> 7) & 0x1FFFFu;
        float norm = 1.0f / (float)(rec >> 24);
        uint2 xw = xb[s];
        float x0 = unlo(xw.x) * norm, x1 = unhi(xw.x) * norm;
        float x2 = unlo(xw.y) * norm, x3 = unhi(xw.y) * norm;
        const float* w = w1 + (size_t)t * 16;   // [2][2][4]
#pragma unroll
        for (int o = 0; o < 4; o++) {
            acc[o]     += x0 * w[o]     + x1 * w[4 + o];
            acc[4 + o] += x2 * w[8 + o] + x3 * w[12 + o];
        }
    }
#pragma unroll
    for (int j = 0; j < 8; j++) {
        acc[j] += __shfl_xor(acc[j], 1);
        acc[j] += __shfl_xor(acc[j], 2);
        acc[j] += __shfl_xor(acc[j], 4);
    }
    if (r != 0) return;
    float4 xn = *(const float4*)(x + (size_t)n * 4);
    float h[8];
#pragma unroll
    for (int j = 0; j < 8; j++) {
        float v = acc[j] + b1[j] + xn.x * root1[j] + xn.y * root1[8 + j]
                + xn.z * root1[16 + j] + xn.w * root1[24 + j];
        h[j] = fmaxf(v, 0.0f);
    }
    h1b[n] = make_uint4(pack2(h[0], h[1]), pack2(h[2], h[3]),
                        pack2(h[4], h[5]), pack2(h[6], h[7]));
}

// ---------------- layer 2: add-aggr + root + bias + relu ----------------
__global__ __launch_bounds__(256) void layer2_kernel(
        const u32* __restrict__ off, const u32* __restrict__ recs,
        const uint4* __restrict__ h1b,
        const float* __restrict__ w2, const float* __restrict__ root2,
        const float* __restrict__ b2, u32* __restrict__ h2b) {
    int gid = blockIdx.x * 256 + threadIdx.x;
    int n = gid >> 3, r = gid & 7;
    if (n >= NN) return;
    float acc[12];
#pragma unroll
    for (int j = 0; j < 12; j++) acc[j] = 0.0f;

    u32 k0 = off[n], k1 = off[n + 1];
    for (u32 k = k0 + r; k < k1; k += 8) {
        u32 rec = __builtin_nontemporal_load(recs + k);
        u32 t = rec & 127u, s = (rec >> 7) & 0x1FFFFu;
        uint4 hw = h1b[s];
        float a0 = unlo(hw.x), a1 = unhi(hw.x), a2 = unlo(hw.y), a3 = unhi(hw.y);
        float a4 = unlo(hw.z), a5 = unhi(hw.z), a6 = unlo(hw.w), a7 = unhi(hw.w);
        const float* w = w2 + (size_t)t * 24;   // [4][2][3]
#pragma unroll
        for (int o = 0; o < 3; o++) {
            acc[o]     += a0 * w[o]      + a1 * w[3 + o];
            acc[3 + o] += a2 * w[6 + o]  + a3 * w[9 + o];
            acc[6 + o] += a4 * w[12 + o] + a5 * w[15 + o];
            acc[9 + o] += a6 * w[18 + o] + a7 * w[21 + o];
        }
    }
#pragma unroll
    for (int j = 0; j < 12; j++) {
        acc[j] += __shfl_xor(acc[j], 1);
        acc[j] += __shfl_xor(acc[j], 2);
        acc[j] += __shfl_xor(acc[j], 4);
    }
    if (r != 0) return;
    uint4 hn = h1b[n];
    float hv[8] = { unlo(hn.x), unhi(hn.x), unlo(hn.y), unhi(hn.y),
                    unlo(hn.z), unhi(hn.z), unlo(hn.w), unhi(hn.w) };
    float h[12];
#pragma unroll
    for (int j = 0; j < 12; j++) {
        float v = acc[j] + b2[j];
#pragma unroll
        for (int i = 0; i < 8; i++) v += hv[i] * root2[i * 12 + j];
        h[j] = fmaxf(v, 0.0f);
    }
    u32* hb = h2b + (size_t)n * 8;             // 32B stride, 24B used
    *(uint4*)hb = make_uint4(pack2(h[0], h[1]), pack2(h[2], h[3]),
                             pack2(h[4], h[5]), pack2(h[6], h[7]));
    *(uint2*)(hb + 4) = make_uint2(pack2(h[8], h[9]), pack2(h[10], h[11]));
}

// ---------------- layer 3: mean-aggr + root + bias + log_softmax ----------------
__global__ __launch_bounds__(256) void layer3_kernel(
        const u32* __restrict__ off, const u32* __restrict__ recs,
        const u32* __restrict__ h2b,
        const float* __restrict__ w3, const float* __restrict__ root3,
        const float* __restrict__ b3, float* __restrict__ out) {
    int gid = blockIdx.x * 256 + threadIdx.x;
    int n = gid >> 3, r = gid & 7;
    if (n >= NN) return;
    float acc[4] = {0.0f, 0.0f, 0.0f, 0.0f};
    u32 k0 = off[n], k1 = off[n + 1];
    for (u32 k = k0 + r; k < k1; k += 8) {
        u32 rec = __builtin_nontemporal_load(recs + k);
        u32 t = rec & 127u, s = (rec >> 7) & 0x1FFFFu;
        float norm = 1.0f / (float)(rec >> 24);
        const u32* hb = h2b + (size_t)s * 8;
        uint4 q = *(const uint4*)hb;
        uint2 p = *(const uint2*)(hb + 4);
        float hsv[12] = { unlo(q.x), unhi(q.x), unlo(q.y), unhi(q.y),
                          unlo(q.z), unhi(q.z), unlo(q.w), unhi(q.w),
                          unlo(p.x), unhi(p.x), unlo(p.y), unhi(p.y) };
        const float* w = w3 + (size_t)t * 24;   // [2][6][2]
        float m0 = 0.0f, m1 = 0.0f, m2 = 0.0f, m3 = 0.0f;
#pragma unroll
        for (int i = 0; i < 6; i++) {
            m0 += hsv[i] * w[i * 2];          m1 += hsv[i] * w[i * 2 + 1];
            m2 += hsv[6 + i] * w[12 + i * 2]; m3 += hsv[6 + i] * w[12 + i * 2 + 1];
        }
        acc[0] += m0 * norm; acc[1] += m1 * norm;
        acc[2] += m2 * norm; acc[3] += m3 * norm;
    }
#pragma unroll
    for (int j = 0; j < 4; j++) {
        acc[j] += __shfl_xor(acc[j], 1);
        acc[j] += __shfl_xor(acc[j], 2);
        acc[j] += __shfl_xor(acc[j], 4);
    }
    if (r != 0) return;
    const u32* hbn = h2b + (size_t)n * 8;
    uint4 qn = *(const uint4*)hbn; uint2 pn = *(const uint2*)(hbn + 4);
    float hv[12] = { unlo(qn.x), unhi(qn.x), unlo(qn.y), unhi(qn.y),
                     unlo(qn.z), unhi(qn.z), unlo(qn.w), unhi(qn.w),
                     unlo(pn.x), unhi(pn.x), unlo(pn.y), unhi(pn.y) };
    float t4[4];
#pragma unroll
    for (int j = 0; j < 4; j++) {
        float v = acc[j] + b3[j];
#pragma unroll
        for (int i = 0; i < 12; i++) v += hv[i] * root3[i * 4 + j];
        t4[j] = v;
    }
    float m = fmaxf(fmaxf(t4[0], t4[1]), fmaxf(t4[2], t4[3]));
    float s = 0.0f;
#pragma unroll
    for (int j = 0; j < 4; j++) s += __expf(t4[j] - m);
    float lse = m + __logf(s);
    *(float4*)(out + (size_t)n * 4) =
        make_float4(t4[0] - lse, t4[1] - lse, t4[2] - lse, t4[3] - lse);
}

extern "C" void kernel_launch(void* const* d_in, const int* in_sizes, int n_in,
                              void* d_out, int out_size, void* d_ws, size_t ws_size,
                              hipStream_t stream) {
    const float* x     = (const float*)d_in[0];
    const int*   ei    = (const int*)d_in[1];   // [2, E]
    const int*   etype = (const int*)d_in[2];
    const float* w1    = (const float*)d_in[3];
    const float* root1 = (const float*)d_in[4];
    const float* b1    = (const float*)d_in[5];
    const float* w2    = (const float*)d_in[6];
    const float* root2 = (const float*)d_in[7];
    const float* b2    = (const float*)d_in[8];
    const float* w3    = (const float*)d_in[9];
    const float* root3 = (const float*)d_in[10];
    const float* b3    = (const float*)d_in[11];
    float* out = (float*)d_out;

    const int* src = ei;
    const int* dst = ei + NE;

    // workspace layout (bytes):
    //   ccnt    : [NB]    u32  @ 0           (pad 1,600)
    //   ccursor : [NB]    u32  @ 1,600       (pad 3,200)
    //   coff    : [NB+1]  u32  @ 3,200       (pad 4,800)
    //   off     : [NN+1]  u32  @ 4,800       (ends 404,804, pad 406,400)
    //   tmp     : [NE]    u32  @ 406,400     (12,800,000)
    //   recs    : [NE]    u32  @ 13,206,400  (12,800,000)
    //   xb      : [NN]    8B   @ 26,006,400  (   800,000)
    //   h1b     : [NN]    16B  @ 26,806,400  ( 1,600,000)
    //   h2b     : [NN]    32B  @ 28,406,400  ( 3,200,000)  -> total 31,606,400
    char* ws = (char*)d_ws;
    u32*   ccnt    = (u32*)ws;
    u32*   ccursor = (u32*)(ws + 1600);
    u32*   coff    = (u32*)(ws + 3200);
    u32*   off     = (u32*)(ws + 4800);
    u32*   tmp     = (u32*)(ws + 406400);
    u32*   recs    = (u32*)(ws + 13206400);
    uint2* xb      = (uint2*)(ws + 26006400);
    uint4* h1b     = (uint4*)(ws + 26806400);
    u32*   h2b     = (u32*)(ws + 28406400);

    hipMemsetAsync(ccnt, 0, NB * sizeof(u32), stream);

    dim3 pgrid(NCHUNK);                      // 782
    dim3 ngrid(NB);                          // 391
    dim3 lgrid((NN * 8 + 255) / 256);        // 3125 (8 lanes/node)

    coarse_count_kernel<<<pgrid, 256, 0, stream>>>(dst, ccnt);
    scan_coff_kernel<<<1, 512, 0, stream>>>(ccnt, coff, ccursor);
    pass1_kernel<<<pgrid, 512, 0, stream>>>(src, dst, etype, ccursor, tmp);
    pass2_kernel<<<ngrid, 512, 0, stream>>>(tmp, coff, off, recs, x, xb);
    layer1_kernel<<<lgrid, 256, 0, stream>>>(off, recs, xb, x, w1, root1, b1, h1b);
    layer2_kernel<<<lgrid, 256, 0, stream>>>(off, recs, h1b, w2, root2, b2, h2b);
    layer3_kernel<<<lgrid, 256, 0, stream>>>(off, recs, h2b, w3, root3, b3, out);
}

// Round 13
// 296.353 us; speedup vs baseline: 1.0893x; 1.0893x over previous
//
#include <hip/hip_runtime.h>
#include <math.h>

#define NN 100000
#define NE 3200000
#define NR 90
#define NB 391          // ceil(NN/256): buckets of 256 nodes (dst>>8)
#define CH 4096         // edges per block in partition passes
#define NCHUNK 782      // ceil(NE/CH)

typedef unsigned int u32;
typedef unsigned short u16;

__device__ inline u32 pack2(float a, float b) {       // bf16(a) lo16, bf16(b) hi16 (RNE)
    u32 ua = __float_as_uint(a); ua += 0x7FFFu + ((ua >> 16) & 1u);
    u32 ub = __float_as_uint(b); ub += 0x7FFFu + ((ub >> 16) & 1u);
    return (ua >> 16) | (ub & 0xFFFF0000u);
}
__device__ inline float unlo(u32 w) { return __uint_as_float(w << 16); }
__device__ inline float unhi(u32 w) { return __uint_as_float(w & 0xFFFF0000u); }

// ---------------- coarse histogram: bucket = dst >> 8 ----------------
__global__ __launch_bounds__(256) void coarse_count_kernel(const int* __restrict__ dst,
                                                           u32* __restrict__ ccnt) {
    __shared__ u32 bh[NB];
    int tid = threadIdx.x;
    for (int b = tid; b < NB; b += 256) bh[b] = 0;
    __syncthreads();
    int c0 = blockIdx.x * CH;
    int c1 = c0 + CH; if (c1 > NE) c1 = NE;
    for (int e = c0 + tid; e < c1; e += 256)
        atomicAdd(&bh[(u32)dst[e] >> 8], 1u);
    __syncthreads();
    for (int b = tid; b < NB; b += 256) {
        u32 c = bh[b];
        if (c) atomicAdd(&ccnt[b], c);
    }
}

// ---------------- exclusive scan of NB coarse counts (1 block) ----------------
__global__ __launch_bounds__(512) void scan_coff_kernel(const u32* __restrict__ ccnt,
                                                        u32* __restrict__ coff,
                                                        u32* __restrict__ ccursor) {
    __shared__ u32 sh[512];
    int tid = threadIdx.x;
    sh[tid] = (tid < NB) ? ccnt[tid] : 0u;
    __syncthreads();
#pragma unroll
    for (int ofs = 1; ofs < 512; ofs <<= 1) {
        u32 v = (tid >= ofs) ? sh[tid - ofs] : 0u;
        __syncthreads();
        sh[tid] += v;
        __syncthreads();
    }
    u32 excl = (tid == 0) ? 0u : sh[tid - 1];
    if (tid < NB) { coff[tid] = excl; ccursor[tid] = excl; }
    if (tid == 0) coff[NB] = NE;
}

// ---------------- pass 1: LDS-staged coarse partition, coalesced run writes ----------------
// tmp entry: (dst&255)<<24 | src<<7 | et
__global__ __launch_bounds__(512) void pass1_kernel(const int* __restrict__ src,
                                                    const int* __restrict__ dst,
                                                    const int* __restrict__ et,
                                                    u32* __restrict__ ccursor,
                                                    u32* __restrict__ tmp) {
    __shared__ u32 cntA[NB];
    __shared__ u32 lcur[NB];
    __shared__ u32 delta[NB];
    __shared__ u32 scanS[512];
    __shared__ u32 lrecs[CH];
    __shared__ u16 lbid[CH];
    int tid = threadIdx.x;
    int c0 = blockIdx.x * CH;
    int c1 = c0 + CH; if (c1 > NE) c1 = NE;
    int nloc = c1 - c0;

    if (tid < NB) cntA[tid] = 0;
    __syncthreads();

    for (int e = c0 + tid; e < c1; e += 512)
        atomicAdd(&cntA[(u32)dst[e] >> 8], 1u);
    __syncthreads();

    scanS[tid] = (tid < NB) ? cntA[tid] : 0u;
    __syncthreads();
#pragma unroll
    for (int ofs = 1; ofs < 512; ofs <<= 1) {
        u32 v = (tid >= ofs) ? scanS[tid - ofs] : 0u;
        __syncthreads();
        scanS[tid] += v;
        __syncthreads();
    }
    if (tid < NB) {
        u32 excl = (tid == 0) ? 0u : scanS[tid - 1];
        lcur[tid] = excl;
        u32 c = cntA[tid];
        delta[tid] = c ? (atomicAdd(&ccursor[tid], c) - excl) : 0u;
    }
    __syncthreads();

    for (int e = c0 + tid; e < c1; e += 512) {
        u32 d = (u32)dst[e];
        u32 b = d >> 8;
        u32 pos = atomicAdd(&lcur[b], 1u);
        lrecs[pos] = ((d & 255u) << 24) | ((u32)src[e] << 7) | (u32)et[e];
        lbid[pos] = (u16)b;
    }
    __syncthreads();

    for (int k = tid; k < nloc; k += 512)
        tmp[delta[lbid[k]] + k] = lrecs[k];
}

// ---------------- pass 2: per-bucket fine sort; recs gets cnt<<24 | src<<7 | et ----------------
__global__ __launch_bounds__(512) void pass2_kernel(const u32* __restrict__ tmp,
                                                    const u32* __restrict__ coff,
                                                    u32* __restrict__ off,
                                                    u32* __restrict__ recs,
                                                    const float* __restrict__ x,
                                                    uint2* __restrict__ xb) {
    __shared__ u32 dh[256];
    __shared__ u32 lcur[256];
    __shared__ u32 cnt32[256 * 23];
    __shared__ u32 sh[256];
    int tid = threadIdx.x;
    int b = blockIdx.x;
    u32 r0 = coff[b], r1 = coff[b + 1];

    if (tid < 256) dh[tid] = 0;
    for (int i = tid; i < 256 * 23; i += 512) cnt32[i] = 0;
    __syncthreads();

    for (u32 k = r0 + tid; k < r1; k += 512)
        atomicAdd(&dh[tmp[k] >> 24], 1u);
    __syncthreads();

    if (tid < 256) sh[tid] = dh[tid];
    __syncthreads();
#pragma unroll
    for (int ofs = 1; ofs < 256; ofs <<= 1) {
        u32 v = (tid >= ofs && tid < 256) ? sh[tid - ofs] : 0u;
        __syncthreads();
        if (tid < 256) sh[tid] += v;
        __syncthreads();
    }
    int n = b * 256 + tid;
    if (tid < 256) {
        u32 excl = (tid == 0) ? 0u : sh[tid - 1];
        if (n < NN) off[n] = r0 + excl;
        lcur[tid] = excl;
    }
    if (b == NB - 1 && tid == 0) off[NN] = NE;
    __syncthreads();

    for (u32 k = r0 + tid; k < r1; k += 512) {
        u32 v = tmp[k];
        u32 ln = v >> 24;
        u32 rec = v & 0xFFFFFFu;
        u32 rel = v & 127u;
        u32 pos = atomicAdd(&lcur[ln], 1u);
        recs[r0 + pos] = rec;
        atomicAdd(&cnt32[ln * 23 + (rel >> 2)], 1u << ((rel & 3u) * 8u));
    }
    __syncthreads();

    if (tid < 256 && n < NN) {
        u32 start = (tid == 0) ? 0u : sh[tid - 1];
        u32 end = sh[tid];
        for (u32 j = start; j < end; j++) {
            u32 rel = recs[r0 + j] & 127u;
            u32 c = (cnt32[tid * 23 + (rel >> 2)] >> ((rel & 3u) * 8u)) & 255u;
            recs[r0 + j] |= c << 24;
        }
        float4 xv = *(const float4*)(x + (size_t)n * 4);
        xb[n] = make_uint2(pack2(xv.x, xv.y), pack2(xv.z, xv.w));
    }
}

// ======== layer kernels: 8 lanes/node (round-9 structure), plain loads, bf16-only tables ========

// ---------------- layer 1: mean-aggr + root + bias + relu ----------------
__global__ __launch_bounds__(256) void layer1_kernel(
        const u32* __restrict__ off, const u32* __restrict__ recs,
        const uint2* __restrict__ xb,
        const float* __restrict__ x, const float* __restrict__ w1,
        const float* __restrict__ root1, const float* __restrict__ b1,
        uint4* __restrict__ h1b) {
    int gid = blockIdx.x * 256 + threadIdx.x;
    int n = gid >> 3, r = gid & 7;
    if (n >= NN) return;
    float acc[8];
#pragma unroll
    for (int j = 0; j < 8; j++) acc[j] = 0.0f;

    u32 k0 = off[n], k1 = off[n + 1];
    for (u32 k = k0 + r; k < k1; k += 8) {
        u32 rec = recs[k];
        u32 t = rec & 127u, s = (rec >> 7) & 0x1FFFFu;
        float norm = 1.0f / (float)(rec >> 24);
        uint2 xw = xb[s];
        float x0 = unlo(xw.x) * norm, x1 = unhi(xw.x) * norm;
        float x2 = unlo(xw.y) * norm, x3 = unhi(xw.y) * norm;
        const float* w = w1 + (size_t)t * 16;   // [2][2][4]
#pragma unroll
        for (int o = 0; o < 4; o++) {
            acc[o]     += x0 * w[o]     + x1 * w[4 + o];
            acc[4 + o] += x2 * w[8 + o] + x3 * w[12 + o];
        }
    }
#pragma unroll
    for (int j = 0; j < 8; j++) {
        acc[j] += __shfl_xor(acc[j], 1);
        acc[j] += __shfl_xor(acc[j], 2);
        acc[j] += __shfl_xor(acc[j], 4);
    }
    if (r != 0) return;
    float4 xn = *(const float4*)(x + (size_t)n * 4);
    float h[8];
#pragma unroll
    for (int j = 0; j < 8; j++) {
        float v = acc[j] + b1[j] + xn.x * root1[j] + xn.y * root1[8 + j]
                + xn.z * root1[16 + j] + xn.w * root1[24 + j];
        h[j] = fmaxf(v, 0.0f);
    }
    h1b[n] = make_uint4(pack2(h[0], h[1]), pack2(h[2], h[3]),
                        pack2(h[4], h[5]), pack2(h[6], h[7]));
}

// ---------------- layer 2: add-aggr + root + bias + relu ----------------
__global__ __launch_bounds__(256) void layer2_kernel(
        const u32* __restrict__ off, const u32* __restrict__ recs,
        const uint4* __restrict__ h1b,
        const float* __restrict__ w2, const float* __restrict__ root2,
        const float* __restrict__ b2, u32* __restrict__ h2b) {
    int gid = blockIdx.x * 256 + threadIdx.x;
    int n = gid >> 3, r = gid & 7;
    if (n >= NN) return;
    float acc[12];
#pragma unroll
    for (int j = 0; j < 12; j++) acc[j] = 0.0f;

    u32 k0 = off[n], k1 = off[n + 1];
    for (u32 k = k0 + r; k < k1; k += 8) {
        u32 rec = recs[k];
        u32 t = rec & 127u, s = (rec >> 7) & 0x1FFFFu;
        uint4 hw = h1b[s];
        float a0 = unlo(hw.x), a1 = unhi(hw.x), a2 = unlo(hw.y), a3 = unhi(hw.y);
        float a4 = unlo(hw.z), a5 = unhi(hw.z), a6 = unlo(hw.w), a7 = unhi(hw.w);
        const float* w = w2 + (size_t)t * 24;   // [4][2][3]
#pragma unroll
        for (int o = 0; o < 3; o++) {
            acc[o]     += a0 * w[o]      + a1 * w[3 + o];
            acc[3 + o] += a2 * w[6 + o]  + a3 * w[9 + o];
            acc[6 + o] += a4 * w[12 + o] + a5 * w[15 + o];
            acc[9 + o] += a6 * w[18 + o] + a7 * w[21 + o];
        }
    }
#pragma unroll
    for (int j = 0; j < 12; j++) {
        acc[j] += __shfl_xor(acc[j], 1);
        acc[j] += __shfl_xor(acc[j], 2);
        acc[j] += __shfl_xor(acc[j], 4);
    }
    if (r != 0) return;
    uint4 hn = h1b[n];
    float hv[8] = { unlo(hn.x), unhi(hn.x), unlo(hn.y), unhi(hn.y),
                    unlo(hn.z), unhi(hn.z), unlo(hn.w), unhi(hn.w) };
    float h[12];
#pragma unroll
    for (int j = 0; j < 12; j++) {
        float v = acc[j] + b2[j];
#pragma unroll
        for (int i = 0; i < 8; i++) v += hv[i] * root2[i * 12 + j];
        h[j] = fmaxf(v, 0.0f);
    }
    u32* hb = h2b + (size_t)n * 8;             // 32B stride, 24B used
    *(uint4*)hb = make_uint4(pack2(h[0], h[1]), pack2(h[2], h[3]),
                             pack2(h[4], h[5]), pack2(h[6], h[7]));
    *(uint2*)(hb + 4) = make_uint2(pack2(h[8], h[9]), pack2(h[10], h[11]));
}

// ---------------- layer 3: mean-aggr + root + bias + log_softmax ----------------
__global__ __launch_bounds__(256) void layer3_kernel(
        const u32* __restrict__ off, const u32* __restrict__ recs,
        const u32* __restrict__ h2b,
        const float* __restrict__ w3, const float* __restrict__ root3,
        const float* __restrict__ b3, float* __restrict__ out) {
    int gid = blockIdx.x * 256 + threadIdx.x;
    int n = gid >> 3, r = gid & 7;
    if (n >= NN) return;
    float acc[4] = {0.0f, 0.0f, 0.0f, 0.0f};
    u32 k0 = off[n], k1 = off[n + 1];
    for (u32 k = k0 + r; k < k1; k += 8) {
        u32 rec = recs[k];
        u32 t = rec & 127u, s = (rec >> 7) & 0x1FFFFu;
        float norm = 1.0f / (float)(rec >> 24);
        const u32* hb = h2b + (size_t)s * 8;
        uint4 q = *(const uint4*)hb;
        uint2 p = *(const uint2*)(hb + 4);
        float hsv[12] = { unlo(q.x), unhi(q.x), unlo(q.y), unhi(q.y),
                          unlo(q.z), unhi(q.z), unlo(q.w), unhi(q.w),
                          unlo(p.x), unhi(p.x), unlo(p.y), unhi(p.y) };
        const float* w = w3 + (size_t)t * 24;   // [2][6][2]
        float m0 = 0.0f, m1 = 0.0f, m2 = 0.0f, m3 = 0.0f;
#pragma unroll
        for (int i = 0; i < 6; i++) {
            m0 += hsv[i] * w[i * 2];          m1 += hsv[i] * w[i * 2 + 1];
            m2 += hsv[6 + i] * w[12 + i * 2]; m3 += hsv[6 + i] * w[12 + i * 2 + 1];
        }
        acc[0] += m0 * norm; acc[1] += m1 * norm;
        acc[2] += m2 * norm; acc[3] += m3 * norm;
    }
#pragma unroll
    for (int j = 0; j < 4; j++) {
        acc[j] += __shfl_xor(acc[j], 1);
        acc[j] += __shfl_xor(acc[j], 2);
        acc[j] += __shfl_xor(acc[j], 4);
    }
    if (r != 0) return;
    const u32* hbn = h2b + (size_t)n * 8;
    uint4 qn = *(const uint4*)hbn; uint2 pn = *(const uint2*)(hbn + 4);
    float hv[12] = { unlo(qn.x), unhi(qn.x), unlo(qn.y), unhi(qn.y),
                     unlo(qn.z), unhi(qn.z), unlo(qn.w), unhi(qn.w),
                     unlo(pn.x), unhi(pn.x), unlo(pn.y), unhi(pn.y) };
    float t4[4];
#pragma unroll
    for (int j = 0; j < 4; j++) {
        float v = acc[j] + b3[j];
#pragma unroll
        for (int i = 0; i < 12; i++) v += hv[i] * root3[i * 4 + j];
        t4[j] = v;
    }
    float m = fmaxf(fmaxf(t4[0], t4[1]), fmaxf(t4[2], t4[3]));
    float s = 0.0f;
#pragma unroll
    for (int j = 0; j < 4; j++) s += __expf(t4[j] - m);
    float lse = m + __logf(s);
    *(float4*)(out + (size_t)n * 4) =
        make_float4(t4[0] - lse, t4[1] - lse, t4[2] - lse, t4[3] - lse);
}

extern "C" void kernel_launch(void* const* d_in, const int* in_sizes, int n_in,
                              void* d_out, int out_size, void* d_ws, size_t ws_size,
                              hipStream_t stream) {
    const float* x     = (const float*)d_in[0];
    const int*   ei    = (const int*)d_in[1];   // [2, E]
    const int*   etype = (const int*)d_in[2];
    const float* w1    = (const float*)d_in[3];
    const float* root1 = (const float*)d_in[4];
    const float* b1    = (const float*)d_in[5];
    const float* w2    = (const float*)d_in[6];
    const float* root2 = (const float*)d_in[7];
    const float* b2    = (const float*)d_in[8];
    const float* w3    = (const float*)d_in[9];
    const float* root3 = (const float*)d_in[10];
    const float* b3    = (const float*)d_in[11];
    float* out = (float*)d_out;

    const int* src = ei;
    const int* dst = ei + NE;

    // workspace layout (bytes):
    //   ccnt    : [NB]    u32  @ 0           (pad 1,600)
    //   ccursor : [NB]    u32  @ 1,600       (pad 3,200)
    //   coff    : [NB+1]  u32  @ 3,200       (pad 4,800)
    //   off     : [NN+1]  u32  @ 4,800       (ends 404,804, pad 406,400)
    //   tmp     : [NE]    u32  @ 406,400     (12,800,000)
    //   recs    : [NE]    u32  @ 13,206,400  (12,800,000)
    //   xb      : [NN]    8B   @ 26,006,400  (   800,000)
    //   h1b     : [NN]    16B  @ 26,806,400  ( 1,600,000)
    //   h2b     : [NN]    32B  @ 28,406,400  ( 3,200,000)  -> total 31,606,400
    char* ws = (char*)d_ws;
    u32*   ccnt    = (u32*)ws;
    u32*   ccursor = (u32*)(ws + 1600);
    u32*   coff    = (u32*)(ws + 3200);
    u32*   off     = (u32*)(ws + 4800);
    u32*   tmp     = (u32*)(ws + 406400);
    u32*   recs    = (u32*)(ws + 13206400);
    uint2* xb      = (uint2*)(ws + 26006400);
    uint4* h1b     = (uint4*)(ws + 26806400);
    u32*   h2b     = (u32*)(ws + 28406400);

    hipMemsetAsync(ccnt, 0, NB * sizeof(u32), stream);

    dim3 pgrid(NCHUNK);                      // 782
    dim3 ngrid(NB);                          // 391
    dim3 lgrid((NN * 8 + 255) / 256);        // 3125 (8 lanes/node)

    coarse_count_kernel<<<pgrid, 256, 0, stream>>>(dst, ccnt);
    scan_coff_kernel<<<1, 512, 0, stream>>>(ccnt, coff, ccursor);
    pass1_kernel<<<pgrid, 512, 0, stream>>>(src, dst, etype, ccursor, tmp);
    pass2_kernel<<<ngrid, 512, 0, stream>>>(tmp, coff, off, recs, x, xb);
    layer1_kernel<<<lgrid, 256, 0, stream>>>(off, recs, xb, x, w1, root1, b1, h1b);
    layer2_kernel<<<lgrid, 256, 0, stream>>>(off, recs, h1b, w2, root2, b2, h2b);
    layer3_kernel<<<lgrid, 256, 0, stream>>>(off, recs, h2b, w3, root3, b3, out);
}

// Round 14
// 275.819 us; speedup vs baseline: 1.1704x; 1.0744x over previous
//
#include <hip/hip_runtime.h>
#include <math.h>

#define NN 100000
#define NE 3200000
#define NR 90
#define NB 391          // buckets of 256 nodes (dst>>8)
#define CH 4096         // edges per block in pass1
#define NCHUNK 782      // ceil(NE/CH)
#define CAP 12288       // padded per-bucket capacity (mean 8192, +45 sigma)

typedef unsigned int u32;
typedef unsigned short u16;

__device__ inline u32 pack2(float a, float b) {       // bf16(a) lo16, bf16(b) hi16 (RNE)
    u32 ua = __float_as_uint(a); ua += 0x7FFFu + ((ua >> 16) & 1u);
    u32 ub = __float_as_uint(b); ub += 0x7FFFu + ((ub >> 16) & 1u);
    return (ua >> 16) | (ub & 0xFFFF0000u);
}
__device__ inline float unlo(u32 w) { return __uint_as_float(w << 16); }
__device__ inline float unhi(u32 w) { return __uint_as_float(w & 0xFFFF0000u); }

// ---------------- pass 1: direct padded-bucket partition (no pre-count) ----------------
// tmp entry: (dst&255)<<24 | src<<7 | et ; bucket b's window is tmp[b*CAP ..]
__global__ __launch_bounds__(512) void pass1_kernel(const int* __restrict__ src,
                                                    const int* __restrict__ dst,
                                                    const int* __restrict__ et,
                                                    u32* __restrict__ ccursor,
                                                    u32* __restrict__ tmp) {
    __shared__ u32 cntA[NB];       // per-bucket count in this chunk
    __shared__ u32 lcur[NB];       // local cursor
    __shared__ u32 delta[NB];      // global run base - local start
    __shared__ u32 scanS[512];
    __shared__ u32 lrecs[CH];      // bucket-sorted records (chunk-local)
    __shared__ u16 lbid[CH];       // bucket id per sorted slot
    int tid = threadIdx.x;
    int c0 = blockIdx.x * CH;
    int c1 = c0 + CH; if (c1 > NE) c1 = NE;
    int nloc = c1 - c0;

    if (tid < NB) cntA[tid] = 0;
    __syncthreads();

    // A: local bucket histogram
    for (int e = c0 + tid; e < c1; e += 512)
        atomicAdd(&cntA[(u32)dst[e] >> 8], 1u);
    __syncthreads();

    // B: local exclusive scan of cntA
    scanS[tid] = (tid < NB) ? cntA[tid] : 0u;
    __syncthreads();
#pragma unroll
    for (int ofs = 1; ofs < 512; ofs <<= 1) {
        u32 v = (tid >= ofs) ? scanS[tid - ofs] : 0u;
        __syncthreads();
        scanS[tid] += v;
        __syncthreads();
    }
    if (tid < NB) {
        u32 excl = (tid == 0) ? 0u : scanS[tid - 1];
        lcur[tid] = excl;
        u32 c = cntA[tid];
        // C: reserve a run in bucket tid's padded window (cursor = offset within bucket)
        delta[tid] = c ? ((u32)tid * CAP + atomicAdd(&ccursor[tid], c) - excl) : 0u;
    }
    __syncthreads();

    // D: scatter into LDS in bucket order
    for (int e = c0 + tid; e < c1; e += 512) {
        u32 d = (u32)dst[e];
        u32 b = d >> 8;
        u32 pos = atomicAdd(&lcur[b], 1u);
        lrecs[pos] = ((d & 255u) << 24) | ((u32)src[e] << 7) | (u32)et[e];
        lbid[pos] = (u16)b;
    }
    __syncthreads();

    // E: coalesced write-out (consecutive k -> consecutive addresses within runs)
    for (int k = tid; k < nloc; k += 512)
        tmp[delta[lbid[k]] + k] = lrecs[k];
}

// ---------------- pass 2: per-bucket fine sort; writes off2=(start,end), recs, xb ----------------
// recs gets cnt<<24 | src<<7 | et, laid out in the same padded bucket windows.
__global__ __launch_bounds__(512) void pass2_kernel(const u32* __restrict__ tmp,
                                                    const u32* __restrict__ ccursor,
                                                    uint2* __restrict__ off2,
                                                    u32* __restrict__ recs,
                                                    const float* __restrict__ x,
                                                    uint2* __restrict__ xb) {
    __shared__ u32 dh[256];          // per-node degree
    __shared__ u32 lcur[256];        // per-node cursor (relative)
    __shared__ u32 cnt32[256 * 23];  // per-(node,rel) u8 counts packed 4/word
    __shared__ u32 sh[256];
    int tid = threadIdx.x;
    int b = blockIdx.x;
    u32 r0 = (u32)b * CAP;
    u32 r1 = r0 + ccursor[b];        // cursor's final value == bucket edge count

    if (tid < 256) dh[tid] = 0;
    for (int i = tid; i < 256 * 23; i += 512) cnt32[i] = 0;
    __syncthreads();

    // A: per-node degrees
    for (u32 k = r0 + tid; k < r1; k += 512)
        atomicAdd(&dh[tmp[k] >> 24], 1u);
    __syncthreads();

    // B: inclusive scan of dh (256 entries)
    if (tid < 256) sh[tid] = dh[tid];
    __syncthreads();
#pragma unroll
    for (int ofs = 1; ofs < 256; ofs <<= 1) {
        u32 v = (tid >= ofs && tid < 256) ? sh[tid - ofs] : 0u;
        __syncthreads();
        if (tid < 256) sh[tid] += v;
        __syncthreads();
    }
    int n = b * 256 + tid;
    if (tid < 256) {
        u32 excl = (tid == 0) ? 0u : sh[tid - 1];
        if (n < NN) off2[n] = make_uint2(r0 + excl, r0 + sh[tid]);
        lcur[tid] = excl;
    }
    __syncthreads();

    // C: fine scatter into this bucket's recs window + per-(node,rel) counts
    for (u32 k = r0 + tid; k < r1; k += 512) {
        u32 v = tmp[k];
        u32 ln = v >> 24;
        u32 rec = v & 0xFFFFFFu;
        u32 rel = v & 127u;
        u32 pos = atomicAdd(&lcur[ln], 1u);
        recs[r0 + pos] = rec;
        atomicAdd(&cnt32[ln * 23 + (rel >> 2)], 1u << ((rel & 3u) * 8u));
    }
    __syncthreads();

    // D: embed per-(node,rel) count into top byte of each rec; pack xb
    if (tid < 256 && n < NN) {
        u32 start = (tid == 0) ? 0u : sh[tid - 1];
        u32 end = sh[tid];
        for (u32 j = start; j < end; j++) {
            u32 rel = recs[r0 + j] & 127u;
            u32 c = (cnt32[tid * 23 + (rel >> 2)] >> ((rel & 3u) * 8u)) & 255u;
            recs[r0 + j] |= c << 24;
        }
        float4 xv = *(const float4*)(x + (size_t)n * 4);
        xb[n] = make_uint2(pack2(xv.x, xv.y), pack2(xv.z, xv.w));
    }
}

// ======== layer kernels: 8 lanes/node, plain loads, bf16-only tables (round-13 best) ========

// ---------------- layer 1: mean-aggr + root + bias + relu ----------------
__global__ __launch_bounds__(256) void layer1_kernel(
        const uint2* __restrict__ off2, const u32* __restrict__ recs,
        const uint2* __restrict__ xb,
        const float* __restrict__ x, const float* __restrict__ w1,
        const float* __restrict__ root1, const float* __restrict__ b1,
        uint4* __restrict__ h1b) {
    int gid = blockIdx.x * 256 + threadIdx.x;
    int n = gid >> 3, r = gid & 7;
    if (n >= NN) return;
    float acc[8];
#pragma unroll
    for (int j = 0; j < 8; j++) acc[j] = 0.0f;

    uint2 o = off2[n];
    u32 k0 = o.x, k1 = o.y;
    for (u32 k = k0 + r; k < k1; k += 8) {
        u32 rec = recs[k];
        u32 t = rec & 127u, s = (rec >> 7) & 0x1FFFFu;
        float norm = 1.0f / (float)(rec >> 24);
        uint2 xw = xb[s];
        float x0 = unlo(xw.x) * norm, x1 = unhi(xw.x) * norm;
        float x2 = unlo(xw.y) * norm, x3 = unhi(xw.y) * norm;
        const float* w = w1 + (size_t)t * 16;   // [2][2][4]
#pragma unroll
        for (int o2 = 0; o2 < 4; o2++) {
            acc[o2]     += x0 * w[o2]     + x1 * w[4 + o2];
            acc[4 + o2] += x2 * w[8 + o2] + x3 * w[12 + o2];
        }
    }
#pragma unroll
    for (int j = 0; j < 8; j++) {
        acc[j] += __shfl_xor(acc[j], 1);
        acc[j] += __shfl_xor(acc[j], 2);
        acc[j] += __shfl_xor(acc[j], 4);
    }
    if (r != 0) return;
    float4 xn = *(const float4*)(x + (size_t)n * 4);
    float h[8];
#pragma unroll
    for (int j = 0; j < 8; j++) {
        float v = acc[j] + b1[j] + xn.x * root1[j] + xn.y * root1[8 + j]
                + xn.z * root1[16 + j] + xn.w * root1[24 + j];
        h[j] = fmaxf(v, 0.0f);
    }
    h1b[n] = make_uint4(pack2(h[0], h[1]), pack2(h[2], h[3]),
                        pack2(h[4], h[5]), pack2(h[6], h[7]));
}

// ---------------- layer 2: add-aggr + root + bias + relu ----------------
__global__ __launch_bounds__(256) void layer2_kernel(
        const uint2* __restrict__ off2, const u32* __restrict__ recs,
        const uint4* __restrict__ h1b,
        const float* __restrict__ w2, const float* __restrict__ root2,
        const float* __restrict__ b2, u32* __restrict__ h2b) {
    int gid = blockIdx.x * 256 + threadIdx.x;
    int n = gid >> 3, r = gid & 7;
    if (n >= NN) return;
    float acc[12];
#pragma unroll
    for (int j = 0; j < 12; j++) acc[j] = 0.0f;

    uint2 o = off2[n];
    u32 k0 = o.x, k1 = o.y;
    for (u32 k = k0 + r; k < k1; k += 8) {
        u32 rec = recs[k];
        u32 t = rec & 127u, s = (rec >> 7) & 0x1FFFFu;
        uint4 hw = h1b[s];
        float a0 = unlo(hw.x), a1 = unhi(hw.x), a2 = unlo(hw.y), a3 = unhi(hw.y);
        float a4 = unlo(hw.z), a5 = unhi(hw.z), a6 = unlo(hw.w), a7 = unhi(hw.w);
        const float* w = w2 + (size_t)t * 24;   // [4][2][3]
#pragma unroll
        for (int o2 = 0; o2 < 3; o2++) {
            acc[o2]     += a0 * w[o2]      + a1 * w[3 + o2];
            acc[3 + o2] += a2 * w[6 + o2]  + a3 * w[9 + o2];
            acc[6 + o2] += a4 * w[12 + o2] + a5 * w[15 + o2];
            acc[9 + o2] += a6 * w[18 + o2] + a7 * w[21 + o2];
        }
    }
#pragma unroll
    for (int j = 0; j < 12; j++) {
        acc[j] += __shfl_xor(acc[j], 1);
        acc[j] += __shfl_xor(acc[j], 2);
        acc[j] += __shfl_xor(acc[j], 4);
    }
    if (r != 0) return;
    uint4 hn = h1b[n];
    float hv[8] = { unlo(hn.x), unhi(hn.x), unlo(hn.y), unhi(hn.y),
                    unlo(hn.z), unhi(hn.z), unlo(hn.w), unhi(hn.w) };
    float h[12];
#pragma unroll
    for (int j = 0; j < 12; j++) {
        float v = acc[j] + b2[j];
#pragma unroll
        for (int i = 0; i < 8; i++) v += hv[i] * root2[i * 12 + j];
        h[j] = fmaxf(v, 0.0f);
    }
    u32* hb = h2b + (size_t)n * 8;             // 32B stride, 24B used
    *(uint4*)hb = make_uint4(pack2(h[0], h[1]), pack2(h[2], h[3]),
                             pack2(h[4], h[5]), pack2(h[6], h[7]));
    *(uint2*)(hb + 4) = make_uint2(pack2(h[8], h[9]), pack2(h[10], h[11]));
}

// ---------------- layer 3: mean-aggr + root + bias + log_softmax ----------------
__global__ __launch_bounds__(256) void layer3_kernel(
        const uint2* __restrict__ off2, const u32* __restrict__ recs,
        const u32* __restrict__ h2b,
        const float* __restrict__ w3, const float* __restrict__ root3,
        const float* __restrict__ b3, float* __restrict__ out) {
    int gid = blockIdx.x * 256 + threadIdx.x;
    int n = gid >> 3, r = gid & 7;
    if (n >= NN) return;
    float acc[4] = {0.0f, 0.0f, 0.0f, 0.0f};
    uint2 o = off2[n];
    u32 k0 = o.x, k1 = o.y;
    for (u32 k = k0 + r; k < k1; k += 8) {
        u32 rec = recs[k];
        u32 t = rec & 127u, s = (rec >> 7) & 0x1FFFFu;
        float norm = 1.0f / (float)(rec >> 24);
        const u32* hb = h2b + (size_t)s * 8;
        uint4 q = *(const uint4*)hb;
        uint2 p = *(const uint2*)(hb + 4);
        float hsv[12] = { unlo(q.x), unhi(q.x), unlo(q.y), unhi(q.y),
                          unlo(q.z), unhi(q.z), unlo(q.w), unhi(q.w),
                          unlo(p.x), unhi(p.x), unlo(p.y), unhi(p.y) };
        const float* w = w3 + (size_t)t * 24;   // [2][6][2]
        float m0 = 0.0f, m1 = 0.0f, m2 = 0.0f, m3 = 0.0f;
#pragma unroll
        for (int i = 0; i < 6; i++) {
            m0 += hsv[i] * w[i * 2];          m1 += hsv[i] * w[i * 2 + 1];
            m2 += hsv[6 + i] * w[12 + i * 2]; m3 += hsv[6 + i] * w[12 + i * 2 + 1];
        }
        acc[0] += m0 * norm; acc[1] += m1 * norm;
        acc[2] += m2 * norm; acc[3] += m3 * norm;
    }
#pragma unroll
    for (int j = 0; j < 4; j++) {
        acc[j] += __shfl_xor(acc[j], 1);
        acc[j] += __shfl_xor(acc[j], 2);
        acc[j] += __shfl_xor(acc[j], 4);
    }
    if (r != 0) return;
    const u32* hbn = h2b + (size_t)n * 8;
    uint4 qn = *(const uint4*)hbn; uint2 pn = *(const uint2*)(hbn + 4);
    float hv[12] = { unlo(qn.x), unhi(qn.x), unlo(qn.y), unhi(qn.y),
                     unlo(qn.z), unhi(qn.z), unlo(qn.w), unhi(qn.w),
                     unlo(pn.x), unhi(pn.x), unlo(pn.y), unhi(pn.y) };
    float t4[4];
#pragma unroll
    for (int j = 0; j < 4; j++) {
        float v = acc[j] + b3[j];
#pragma unroll
        for (int i = 0; i < 12; i++) v += hv[i] * root3[i * 4 + j];
        t4[j] = v;
    }
    float m = fmaxf(fmaxf(t4[0], t4[1]), fmaxf(t4[2], t4[3]));
    float s = 0.0f;
#pragma unroll
    for (int j = 0; j < 4; j++) s += __expf(t4[j] - m);
    float lse = m + __logf(s);
    *(float4*)(out + (size_t)n * 4) =
        make_float4(t4[0] - lse, t4[1] - lse, t4[2] - lse, t4[3] - lse);
}

extern "C" void kernel_launch(void* const* d_in, const int* in_sizes, int n_in,
                              void* d_out, int out_size, void* d_ws, size_t ws_size,
                              hipStream_t stream) {
    const float* x     = (const float*)d_in[0];
    const int*   ei    = (const int*)d_in[1];   // [2, E]
    const int*   etype = (const int*)d_in[2];
    const float* w1    = (const float*)d_in[3];
    const float* root1 = (const float*)d_in[4];
    const float* b1    = (const float*)d_in[5];
    const float* w2    = (const float*)d_in[6];
    const float* root2 = (const float*)d_in[7];
    const float* b2    = (const float*)d_in[8];
    const float* w3    = (const float*)d_in[9];
    const float* root3 = (const float*)d_in[10];
    const float* b3    = (const float*)d_in[11];
    float* out = (float*)d_out;

    const int* src = ei;
    const int* dst = ei + NE;

    // workspace layout (bytes):
    //   ccursor : [NB]      u32   @ 0           (1,564 -> pad 1,600)
    //   off2    : [NN]      uint2 @ 1,600       (800,000 -> ends 801,600, pad 801,664)
    //   tmp     : [NB*CAP]  u32   @ 801,664     (19,218,432 -> ends 20,020,096, pad 20,020,224)
    //   recs    : [NB*CAP]  u32   @ 20,020,224  (19,218,432 -> ends 39,238,656)
    //   xb      : [NN]      8B    @ 39,238,656  (   800,000)
    //   h1b     : [NN]      16B   @ 40,038,656  ( 1,600,000)
    //   h2b     : [NN]      32B   @ 41,638,656  ( 3,200,000)  -> total 44,838,656
    char* ws = (char*)d_ws;
    u32*   ccursor = (u32*)ws;
    uint2* off2    = (uint2*)(ws + 1600);
    u32*   tmp     = (u32*)(ws + 801664);
    u32*   recs    = (u32*)(ws + 20020224);
    uint2* xb      = (uint2*)(ws + 39238656);
    uint4* h1b     = (uint4*)(ws + 40038656);
    u32*   h2b     = (u32*)(ws + 41638656);

    hipMemsetAsync(ccursor, 0, NB * sizeof(u32), stream);

    dim3 pgrid(NCHUNK);                      // 782
    dim3 ngrid(NB);                          // 391
    dim3 lgrid((NN * 8 + 255) / 256);        // 3125 (8 lanes/node)

    pass1_kernel<<<pgrid, 512, 0, stream>>>(src, dst, etype, ccursor, tmp);
    pass2_kernel<<<ngrid, 512, 0, stream>>>(tmp, ccursor, off2, recs, x, xb);
    layer1_kernel<<<lgrid, 256, 0, stream>>>(off2, recs, xb, x, w1, root1, b1, h1b);
    layer2_kernel<<<lgrid, 256, 0, stream>>>(off2, recs, h1b, w2, root2, b2, h2b);
    layer3_kernel<<<lgrid, 256, 0, stream>>>(off2, recs, h2b, w3, root3, b3, out);
}